// Round 1
// baseline (427.364 us; speedup 1.0000x reference)
//
#include <hip/hip_runtime.h>

#define HW_ 4096
#define KSEL 409   // int(0.1 * 4096)

// Wave-0 top-down crossing search over a histogram in LDS.
// Finds largest bin b such that count(bins > b) < kneed <= count(bins >= b).
// Writes *s_bin = b, *s_rem = kneed - count(bins > b).
__device__ __forceinline__ void scan_find(unsigned* hist, int N, unsigned kneed,
                                          unsigned* s_bin, unsigned* s_rem, int t) {
  if (t < 64) {
    const int C = N >> 6;              // bins per lane
    const int base = N - (t + 1) * C;  // lane 0 covers the TOP chunk
    unsigned sum = 0;
    for (int j = 0; j < C; ++j) sum += hist[base + j];
    unsigned inc = sum;
    #pragma unroll
    for (int off = 1; off < 64; off <<= 1) {
      unsigned u = __shfl_up(inc, off);
      if (t >= off) inc += u;
    }
    unsigned long long m = __ballot(inc >= kneed);
    int cl = __ffsll(m) - 1;           // first (topmost) crossing lane
    if (t == cl) {
      unsigned cum = inc - sum;        // count in chunks strictly above mine
      for (int j = C - 1; j >= 0; --j) {
        unsigned h = hist[base + j];
        if (cum + h >= kneed) { *s_bin = (unsigned)(base + j); *s_rem = kneed - cum; break; }
        cum += h;
      }
    }
  }
}

extern "C" __global__ void __launch_bounds__(256, 4)
topk_kern(const float* __restrict__ x, float* __restrict__ out) {
  __shared__ unsigned hist[2048];
  __shared__ unsigned sb[2];
  const int t = threadIdx.x;
  const size_t rowoff = (size_t)blockIdx.x * HW_;
  const float4* xr = (const float4*)(x + rowoff);
  float4* orow = (float4*)(out + rowoff);

  // Load 16 elements per thread as 4x float4 (coalesced), keep in registers.
  float4 v[4];
  unsigned ab[16];
  #pragma unroll
  for (int j = 0; j < 4; ++j) {
    v[j] = xr[t + j * 256];
    ab[4 * j + 0] = __float_as_uint(v[j].x) & 0x7FFFFFFFu;
    ab[4 * j + 1] = __float_as_uint(v[j].y) & 0x7FFFFFFFu;
    ab[4 * j + 2] = __float_as_uint(v[j].z) & 0x7FFFFFFFu;
    ab[4 * j + 3] = __float_as_uint(v[j].w) & 0x7FFFFFFFu;
  }

  // ---- pass 1: top 11 bits (ab>>20), 2048 bins ----
  #pragma unroll
  for (int j = 0; j < 8; ++j) hist[t + j * 256] = 0;
  __syncthreads();
  #pragma unroll
  for (int i = 0; i < 16; ++i) atomicAdd(&hist[ab[i] >> 20], 1u);
  __syncthreads();
  scan_find(hist, 2048, KSEL, &sb[0], &sb[1], t);
  __syncthreads();
  const unsigned b1 = sb[0];
  const unsigned k2 = sb[1];

  // ---- pass 2: mid 10 bits among (ab>>20)==b1, 1024 bins ----
  #pragma unroll
  for (int j = 0; j < 4; ++j) hist[t + j * 256] = 0;
  __syncthreads();
  #pragma unroll
  for (int i = 0; i < 16; ++i)
    if ((ab[i] >> 20) == b1) atomicAdd(&hist[(ab[i] >> 10) & 0x3FFu], 1u);
  __syncthreads();
  scan_find(hist, 1024, k2, &sb[0], &sb[1], t);
  __syncthreads();
  const unsigned b2 = sb[0];
  const unsigned k3 = sb[1];
  const unsigned P = (b1 << 10) | b2;   // top 21 bits of threshold

  // ---- pass 3: low 10 bits among (ab>>10)==P, 1024 bins ----
  #pragma unroll
  for (int j = 0; j < 4; ++j) hist[t + j * 256] = 0;
  __syncthreads();
  #pragma unroll
  for (int i = 0; i < 16; ++i)
    if ((ab[i] >> 10) == P) atomicAdd(&hist[ab[i] & 0x3FFu], 1u);
  __syncthreads();
  scan_find(hist, 1024, k3, &sb[0], &sb[1], t);
  __syncthreads();
  const unsigned b3 = sb[0];
  const unsigned rem = sb[1];           // how many ==T to keep
  const unsigned ceq = hist[b3];        // how many ==T exist
  const unsigned T = (P << 10) | b3;    // exact k-th largest abs bit pattern

  unsigned keepmask = 0;
  #pragma unroll
  for (int i = 0; i < 16; ++i) if (ab[i] > T) keepmask |= (1u << i);

  if (rem == ceq) {
    // no tie truncation needed: keep every element equal to T
    #pragma unroll
    for (int i = 0; i < 16; ++i) if (ab[i] == T) keepmask |= (1u << i);
  } else {
    // Rare exact-bitwise-tie path: keep the first `rem` equals in index order.
    // Element index = 4*t + 1024*j + e  -> lexicographic (j, t, e).
    __syncthreads();  // all threads have read ceq before hist is reused
    #pragma unroll
    for (int j = 0; j < 4; ++j) {
      unsigned c = 0;
      #pragma unroll
      for (int e = 0; e < 4; ++e) if (ab[4 * j + e] == T) ++c;
      hist[j * 256 + t] = c;
    }
    __syncthreads();
    if (t == 0) {  // serial exclusive prefix in index order (rare path)
      unsigned run = 0;
      for (int i = 0; i < 1024; ++i) { unsigned h = hist[i]; hist[i] = run; run += h; }
    }
    __syncthreads();
    #pragma unroll
    for (int j = 0; j < 4; ++j) {
      unsigned r = hist[j * 256 + t];
      #pragma unroll
      for (int e = 0; e < 4; ++e) {
        if (ab[4 * j + e] == T) { if (r < rem) keepmask |= (1u << (4 * j + e)); ++r; }
      }
    }
  }

  // ---- write out (coalesced float4) ----
  #pragma unroll
  for (int j = 0; j < 4; ++j) {
    float4 o;
    o.x = ((keepmask >> (4 * j + 0)) & 1u) ? v[j].x : 0.0f;
    o.y = ((keepmask >> (4 * j + 1)) & 1u) ? v[j].y : 0.0f;
    o.z = ((keepmask >> (4 * j + 2)) & 1u) ? v[j].z : 0.0f;
    o.w = ((keepmask >> (4 * j + 3)) & 1u) ? v[j].w : 0.0f;
    orow[t + j * 256] = o;
  }
}

extern "C" void kernel_launch(void* const* d_in, const int* in_sizes, int n_in,
                              void* d_out, int out_size, void* d_ws, size_t ws_size,
                              hipStream_t stream) {
  const float* x = (const float*)d_in[0];
  float* out = (float*)d_out;
  const int rows = in_sizes[0] / HW_;  // 64*256 = 16384 rows of 4096
  topk_kern<<<dim3(rows), dim3(256), 0, stream>>>(x, out);
}